// Round 6
// baseline (792.198 us; speedup 1.0000x reference)
//
#include <hip/hip_runtime.h>
#include <hip/hip_bf16.h>
#include <stdint.h>

// Problem dims
#define Dd 1024
#define Ee 8
#define Ff 2816
#define Tt 8192    // B*S tokens
#define Pp 16384   // Tt * K pairs

#define BMT 256            // M tile
#define MAXT 72            // max M-tiles: Pp/256 + Ee

using bf16x8 = __attribute__((ext_vector_type(8))) short;
using f32x4  = __attribute__((ext_vector_type(4))) float;

__device__ __forceinline__ uint16_t f2bf(float f) {
    union { float f; uint32_t u; } v; v.f = f;
    return (uint16_t)((v.u + 0x7fffu + ((v.u >> 16) & 1u)) >> 16);
}
__device__ __forceinline__ uint32_t pack2(float a, float b) {
    return (uint32_t)f2bf(a) | ((uint32_t)f2bf(b) << 16);
}
__device__ __forceinline__ uint4 pack8(float4 a, float4 b) {
    uint4 r; r.x = pack2(a.x, a.y); r.y = pack2(a.z, a.w);
    r.z = pack2(b.x, b.y); r.w = pack2(b.z, b.w); return r;
}
// XOR swizzle within a 128B LDS row (G4)
__device__ __forceinline__ int swz(int row, int cb) {
    return row * 128 + (cb ^ ((row & 7) << 4));
}
__device__ __forceinline__ void gload16(const void* g, void* lds) {
    __builtin_amdgcn_global_load_lds(
        (const __attribute__((address_space(1))) uint32_t*)(uintptr_t)g,
        (__attribute__((address_space(3))) uint32_t*)(uintptr_t)lds,
        16, 0, 0);
}
__device__ __forceinline__ int xcd_swz(int b, int nwg) {
    int xcd = b & 7, pos = b >> 3;
    int q = nwg >> 3, r = nwg & 7;
    return (xcd < r ? xcd * (q + 1) : r * (q + 1) + (xcd - r) * q) + pos;
}

// ---------------- Router ----------------
__global__ __launch_bounds__(256) void router_kernel(
    const float* __restrict__ x, const float* __restrict__ gw,
    float* __restrict__ usage_bank, int* __restrict__ counts,
    int* __restrict__ tok_i, float* __restrict__ tok_w)
{
    __shared__ float us[Ee];
    int tid = threadIdx.x;
    if (tid < Ee) us[tid] = 0.f;
    __syncthreads();
    int wave = tid >> 6, lane = tid & 63;
    int t = blockIdx.x * 4 + wave;

    float xr[16];
    const float* xp = x + (size_t)t * Dd;
    #pragma unroll
    for (int j = 0; j < 16; ++j) xr[j] = xp[lane + 64 * j];

    float logits[Ee];
    #pragma unroll
    for (int e = 0; e < Ee; ++e) {
        const float* gp = gw + e * Dd;
        float s = 0.f;
        #pragma unroll
        for (int j = 0; j < 16; ++j) s += xr[j] * gp[lane + 64 * j];
        #pragma unroll
        for (int m = 1; m < 64; m <<= 1) s += __shfl_xor(s, m, 64);
        logits[e] = s;
    }
    float v1 = -1e30f, v2 = -1e30f; int i1 = 0, i2 = 0;
    #pragma unroll
    for (int e = 0; e < Ee; ++e) {
        float l = logits[e];
        if (l > v1) { v2 = v1; i2 = i1; v1 = l; i1 = e; }
        else if (l > v2) { v2 = l; i2 = e; }
    }
    float ex2 = expf(v2 - v1);
    float w1 = 1.f / (1.f + ex2);
    float w2 = ex2 * w1;
    float p[Ee]; float se = 0.f;
    #pragma unroll
    for (int e = 0; e < Ee; ++e) { p[e] = expf(logits[e] - v1); se += p[e]; }
    float inv = 1.f / se;
    if (lane == 0) {
        #pragma unroll
        for (int e = 0; e < Ee; ++e) atomicAdd(&us[e], p[e] * inv);
        atomicAdd(&counts[i1], 1);
        atomicAdd(&counts[i2], 1);
        tok_i[t * 2] = i1; tok_i[t * 2 + 1] = i2;
        tok_w[t * 2] = w1; tok_w[t * 2 + 1] = w2;
    }
    __syncthreads();
    if (tid < Ee) atomicAdd(&usage_bank[(blockIdx.x & 63) * Ee + tid], us[tid]);
}

// ---------------- Scan: aux + offsets + tile list ----------------
__global__ void scan_kernel(const float* __restrict__ usage_bank,
                            const int* __restrict__ counts,
                            int* __restrict__ seg_off, int* __restrict__ cursor,
                            int* __restrict__ ntiles, int* __restrict__ tile_e,
                            int* __restrict__ tile_row0, float* __restrict__ out_aux)
{
    int tid = threadIdx.x;
    __shared__ float us[Ee];
    if (tid < Ee) {
        float s = 0.f;
        for (int b = 0; b < 64; ++b) s += usage_bank[b * Ee + tid];
        us[tid] = s / (float)Tt;
    }
    __syncthreads();
    if (tid == 0) {
        float aux = 0.f;
        for (int e = 0; e < Ee; ++e) { float d = us[e] - 0.125f; aux += d * d; }
        *out_aux = aux;
        int off = 0;
        for (int e = 0; e < Ee; ++e) { seg_off[e] = off; cursor[e] = off; off += counts[e]; }
        seg_off[Ee] = off;
        int ti = 0;
        for (int e = 0; e < Ee; ++e) {
            int so = seg_off[e], cnt = counts[e];
            for (int r = 0; r < cnt; r += BMT) { tile_e[ti] = e; tile_row0[ti] = so + r; ++ti; }
        }
        *ntiles = ti;   // <= MAXT
    }
}

// ---------------- Build pair lists (+ token->slot map) ----------------
__global__ __launch_bounds__(256) void build_kernel(
    const int* __restrict__ tok_i, const float* __restrict__ tok_w,
    int* __restrict__ cursor, int* __restrict__ token_id, float* __restrict__ pair_w,
    int* __restrict__ pos)
{
    int t = blockIdx.x * 256 + threadIdx.x;
    if (t >= Tt) return;
    int i1 = tok_i[t * 2], i2 = tok_i[t * 2 + 1];
    int s1 = atomicAdd(&cursor[i1], 1);
    token_id[s1] = t; pair_w[s1] = tok_w[t * 2];     pos[t * 2] = s1;
    int s2 = atomicAdd(&cursor[i2], 1);
    token_id[s2] = t; pair_w[s2] = tok_w[t * 2 + 1]; pos[t * 2 + 1] = s2;
}

// ---------------- Gather x rows -> bf16 Xg[pair, D] ----------------
__global__ __launch_bounds__(256) void gather_kernel(
    const float* __restrict__ x, const int* __restrict__ token_id,
    uint16_t* __restrict__ Xg)
{
    int wave = threadIdx.x >> 6, lane = threadIdx.x & 63;
    int r = blockIdx.x * 4 + wave;
    if (r >= Pp) return;
    int t = token_id[r];
    const float4* src = (const float4*)(x + (size_t)t * Dd) + lane * 4;
    float4 f0 = src[0], f1 = src[1], f2 = src[2], f3 = src[3];
    uint4* dst = (uint4*)(Xg + (size_t)r * Dd) + lane * 2;
    dst[0] = pack8(f0, f1);
    dst[1] = pack8(f2, f3);
}

// ---------------- fp32 -> bf16 plain conversion (w_down) ----------------
__global__ __launch_bounds__(256) void conv_kernel(
    const float* __restrict__ src, uint16_t* __restrict__ dst, long long n)
{
    long long i = ((long long)blockIdx.x * 256 + threadIdx.x) * 8;
    if (i >= n) return;
    const float4* s = (const float4*)(src + i);
    float4 a = s[0], b = s[1];
    *(uint4*)(dst + i) = pack8(a, b);
}

// ---------------- gate/up -> interleaved bf16 W1b ----------------
// W1b[e] has 5632 rows: row (f>>4)*32 + (f&15) = gate f ; +16 = up f.
__global__ __launch_bounds__(256) void conv_w1_kernel(
    const float* __restrict__ gsrc, const float* __restrict__ usrc,
    uint16_t* __restrict__ dst)
{
    long long i = ((long long)blockIdx.x * 256 + threadIdx.x) * 8;
    if (i >= (long long)Ee * Ff * Dd) return;
    int d = (int)(i & (Dd - 1));
    long long row = i >> 10;            // e*Ff + f
    int e = (int)(row / Ff), f = (int)(row - (long long)e * Ff);
    size_t rg = (size_t)e * 5632 + (size_t)(f >> 4) * 32 + (f & 15);
    const float4* sg = (const float4*)(gsrc + i);
    *(uint4*)(dst + rg * 1024 + d) = pack8(sg[0], sg[1]);
    const float4* su = (const float4*)(usrc + i);
    *(uint4*)(dst + (rg + 16) * 1024 + d) = pack8(su[0], su[1]);
}

// ---------------- Phase-pipelined GEMM (m201-style schedule) ----------------
// BM=256, BK=64, 512 threads (8 waves), double-buffered LDS, counted vmcnt.
// Per K-tile: 2*G phases, each {ds_read 4-8 frags; barrier; lgkm0; 16 MFMA; barrier}.
// MODE 0: gemm1 (A=Xg, B=W1b interleaved, BN=256, epilogue silu*u -> hbuf bf16)
// MODE 1: gemm2 store (A=hbuf, B=wd_b, BN=128, epilogue P[pr] fp32)
// MODE 2: gemm2 atomic (epilogue atomicAdd into out)
#define LGKM0 asm volatile("s_waitcnt lgkmcnt(0)" ::: "memory")
#define SCHED0 __builtin_amdgcn_sched_barrier(0)

template<int NKT, int BN, int MODE>
__global__ __launch_bounds__(512, 2) void gemm_pipe(
    const uint16_t* __restrict__ Abase, const uint16_t* __restrict__ Bbase,
    const int* __restrict__ seg_off, const int* __restrict__ tile_e,
    const int* __restrict__ tile_row0, const int* __restrict__ ntiles,
    const int* __restrict__ token_id, const float* __restrict__ pair_w,
    uint16_t* __restrict__ hbuf, float* __restrict__ Pbuf, float* __restrict__ out,
    int tile0, int Tc, int nwg)
{
    constexpr int NW = BN / 64;            // waves along N
    constexpr int MW = 8 / NW;             // waves along M
    constexpr int MF = 256 / (MW * 16);    // m-frags per wave (8 / 4)
    constexpr int G  = MF / 4;             // m-frag groups = phases per kk (2 / 1)
    constexpr int LDA = (MODE == 0) ? Dd : Ff;
    constexpr int LDB = (MODE == 0) ? Dd : Ff;
    constexpr int BROUNDS = BN / 64;
    constexpr int BUFB = 32768 + BN * 128;

    int wgid = xcd_swz(blockIdx.x, nwg);
    int nt = wgid / Tc, lt = wgid - nt * Tc;
    int tidx = tile0 + lt;
    if (tidx >= *ntiles) return;
    int e = tile_e[tidx];
    int row0 = tile_row0[tidx];
    int rows = seg_off[e + 1] - row0; if (rows > BMT) rows = BMT;
    int slot = lt * BMT;

    __shared__ uint4 lds4[(2 * BUFB) / 16];
    char* lds = (char*)lds4;

    int tid = threadIdx.x, lane = tid & 63, wv = tid >> 6;
    int wr = wv / NW, wc = wv % NW;

    // per-lane inverse-swizzled staging sources (rule #21: LDS dest linear)
    int srow = wv * 8 + (lane >> 3);
    int csw = ((lane & 7) ^ (lane >> 3)) * 8;
    const uint16_t* aP;
    const uint16_t* bP;
    if constexpr (MODE == 0) {
        aP = Abase + (size_t)(row0 + srow) * LDA + csw;
        bP = Bbase + ((size_t)e * 5632 + nt * (size_t)BN + srow) * LDB + csw;
    } else {
        aP = Abase + (size_t)(slot + srow) * LDA + csw;
        bP = Bbase + ((size_t)e * Dd + nt * (size_t)BN + srow) * LDB + csw;
    }

    auto STAGE = [&](int kt, int c) {
        char* base = lds + c * BUFB;
        #pragma unroll
        for (int i = 0; i < 4; ++i)
            gload16(aP + (size_t)(i * 64) * LDA + kt * 64, base + i * 8192 + wv * 1024);
        #pragma unroll
        for (int i = 0; i < BROUNDS; ++i)
            gload16(bP + (size_t)(i * 64) * LDB + kt * 64, base + 32768 + i * 8192 + wv * 1024);
    };

    f32x4 acc[MF][4];
    f32x4 zero4 = {0.f, 0.f, 0.f, 0.f};
    #pragma unroll
    for (int m = 0; m < MF; ++m)
        #pragma unroll
        for (int n = 0; n < 4; ++n) acc[m][n] = zero4;

    STAGE(0, 0);
    STAGE(1, 1);
    // wait tile 0 resident (tile 1's loads stay in flight)
    if constexpr (BN == 256) asm volatile("s_waitcnt vmcnt(8)" ::: "memory");
    else                     asm volatile("s_waitcnt vmcnt(6)" ::: "memory");
    __builtin_amdgcn_s_barrier();
    SCHED0;

    #pragma unroll 1
    for (int t = 0; t < NKT; ++t) {
        int c = t & 1;
        char* smA = lds + c * BUFB;
        char* smB = smA + 32768;
        #pragma unroll
        for (int kk = 0; kk < 2; ++kk) {
            int cb = kk * 64 + ((lane >> 4) << 4);
            bf16x8 bk[4];
            #pragma unroll
            for (int g = 0; g < G; ++g) {
                // ---- phase (kk,g): issue reads, barrier, wait, 16 MFMA, barrier
                bf16x8 a[4];
                #pragma unroll
                for (int m = 0; m < 4; ++m)
                    a[m] = *(const bf16x8*)(smA + swz(wr * (MF * 16) + (g * 4 + m) * 16 + (lane & 15), cb));
                if (g == 0) {
                    #pragma unroll
                    for (int n = 0; n < 4; ++n)
                        bk[n] = *(const bf16x8*)(smB + swz(wc * 64 + n * 16 + (lane & 15), cb));
                }
                __builtin_amdgcn_s_barrier();   // before lgkm0: waves overlap LDS & MFMA
                LGKM0;
                SCHED0;                          // rule #18: pin MFMA after the wait
                __builtin_amdgcn_s_setprio(1);
                #pragma unroll
                for (int m = 0; m < 4; ++m)
                    #pragma unroll
                    for (int n = 0; n < 4; ++n)
                        acc[g * 4 + m][n] = __builtin_amdgcn_mfma_f32_16x16x32_bf16(
                            a[m], bk[n], acc[g * 4 + m][n], 0, 0, 0);
                __builtin_amdgcn_s_setprio(0);
                SCHED0;
                __builtin_amdgcn_s_barrier();   // phase fence (keeps waves in lockstep phase)
            }
        }
        // all reads of buf c done (every wave passed its last lgkm0 + barrier)
        if (t + 2 < NKT) {
            STAGE(t + 2, c);
            // counted: wait tile t+1 (issued last iter) resident; t+2 stays in flight
            if constexpr (BN == 256) asm volatile("s_waitcnt vmcnt(8)" ::: "memory");
            else                     asm volatile("s_waitcnt vmcnt(6)" ::: "memory");
        } else {
            asm volatile("s_waitcnt vmcnt(0)" ::: "memory");   // tail drain
        }
        __builtin_amdgcn_s_barrier();
        SCHED0;
    }

    if constexpr (MODE == 0) {
        // n-frags alternate gate/up: h = silu(g)*u, 2 h-cols per m-frag
        int hc = nt * 128 + wc * 32 + (lane & 15);
        #pragma unroll
        for (int m = 0; m < MF; ++m) {
            #pragma unroll
            for (int g = 0; g < 4; ++g) {
                int rr = wr * 128 + m * 16 + (lane >> 4) * 4 + g;
                if (rr < rows) {
                    uint16_t* hp = hbuf + (size_t)(slot + rr) * Ff + hc;
                    float g0 = acc[m][0][g], u0 = acc[m][1][g];
                    hp[0]  = f2bf(g0 * u0 / (1.f + expf(-g0)));
                    float g1 = acc[m][2][g], u1 = acc[m][3][g];
                    hp[16] = f2bf(g1 * u1 / (1.f + expf(-g1)));
                }
            }
        }
    } else if constexpr (MODE == 1) {
        int col = nt * 128 + wc * 64 + (lane & 15);
        #pragma unroll
        for (int m = 0; m < MF; ++m) {
            #pragma unroll
            for (int g = 0; g < 4; ++g) {
                int rr = wr * 64 + m * 16 + (lane >> 4) * 4 + g;
                if (rr < rows) {
                    float* pp = Pbuf + (size_t)(row0 + rr) * Dd + col;
                    pp[0]  = acc[m][0][g];
                    pp[16] = acc[m][1][g];
                    pp[32] = acc[m][2][g];
                    pp[48] = acc[m][3][g];
                }
            }
        }
    } else {
        int col = nt * 128 + wc * 64 + (lane & 15);
        #pragma unroll
        for (int m = 0; m < MF; ++m) {
            #pragma unroll
            for (int g = 0; g < 4; ++g) {
                int rr = wr * 64 + m * 16 + (lane >> 4) * 4 + g;
                if (rr < rows) {
                    int pr = row0 + rr;
                    int tok = token_id[pr];
                    float w = pair_w[pr];
                    float* op = out + (size_t)tok * Dd + col;
                    atomicAdd(op + 0,  w * acc[m][0][g]);
                    atomicAdd(op + 16, w * acc[m][1][g]);
                    atomicAdd(op + 32, w * acc[m][2][g]);
                    atomicAdd(op + 48, w * acc[m][3][g]);
                }
            }
        }
    }
}

// ---------------- Combine: out[t] = w1*P[s1] + w2*P[s2] ----------------
__global__ __launch_bounds__(256) void combine_kernel(
    const float* __restrict__ P, const int* __restrict__ pos,
    const float* __restrict__ tok_w, float* __restrict__ out)
{
    int t = blockIdx.x;
    int d = threadIdx.x * 4;
    int s1 = pos[t * 2], s2 = pos[t * 2 + 1];
    float w1 = tok_w[t * 2], w2 = tok_w[t * 2 + 1];
    float4 a = *(const float4*)(P + (size_t)s1 * Dd + d);
    float4 b = *(const float4*)(P + (size_t)s2 * Dd + d);
    float4 o;
    o.x = w1 * a.x + w2 * b.x; o.y = w1 * a.y + w2 * b.y;
    o.z = w1 * a.z + w2 * b.z; o.w = w1 * a.w + w2 * b.w;
    *(float4*)(out + (size_t)t * Dd + d) = o;
}

// ---------------- Host launch ----------------
extern "C" void kernel_launch(void* const* d_in, const int* in_sizes, int n_in,
                              void* d_out, int out_size, void* d_ws, size_t ws_size,
                              hipStream_t stream)
{
    const float* x     = (const float*)d_in[0];
    const float* gw    = (const float*)d_in[1];
    const float* wgate = (const float*)d_in[2];
    const float* wup   = (const float*)d_in[3];
    const float* wdown = (const float*)d_in[4];
    float* out = (float*)d_out;

    char* ws = (char*)d_ws;
    float* usage_bank = (float*)(ws);
    int*   counts     = (int*)(ws + 2048);
    int*   seg_off    = (int*)(ws + 2112);
    int*   cursor     = (int*)(ws + 2176);
    int*   ntiles     = (int*)(ws + 2240);
    int*   tile_e     = (int*)(ws + 4096);
    int*   tile_row0  = (int*)(ws + 5120);
    int*   tok_i      = (int*)(ws + 8192);
    float* tok_w      = (float*)(ws + 73728);
    int*   token_id   = (int*)(ws + 139264);
    float* pair_w     = (float*)(ws + 204800);
    int*   pos        = (int*)(ws + 270336);
    const size_t CTRL  = 335872;
    const size_t TILEB = (size_t)BMT * Ff * 2;          // 1,441,792 B per h-tile
    const size_t XgB   = (size_t)(Pp + BMT) * Dd * 2;   // 34.1 MB (padded)
    const size_t W1B   = 2ull * Ee * Ff * Dd * 2;       // 92.3 MB interleaved gate/up
    const size_t WDB   = (size_t)Ee * Dd * Ff * 2;      // 46.1 MB
    const size_t PB    = (size_t)Pp * Dd * 4;           // 67.1 MB fp32 per-pair rows

    if (ws_size >= 4096) hipMemsetAsync(ws, 0, 4096, stream);
    size_t fixed = CTRL + XgB + W1B + WDB;
    if (ws_size < fixed + TILEB) {   // cannot run the fast path; fail gracefully (no OOB)
        hipMemsetAsync(d_out, 0, (size_t)out_size * 4, stream);
        return;
    }

    router_kernel<<<Tt / 4, 256, 0, stream>>>(x, gw, usage_bank, counts, tok_i, tok_w);
    scan_kernel<<<1, 64, 0, stream>>>(usage_bank, counts, seg_off, cursor,
                                      ntiles, tile_e, tile_row0, out + (out_size - 1));
    build_kernel<<<Tt / 256, 256, 0, stream>>>(tok_i, tok_w, cursor, token_id, pair_w, pos);

    uint16_t* Xg   = (uint16_t*)(ws + CTRL);
    uint16_t* W1b  = (uint16_t*)(ws + CTRL + XgB);
    uint16_t* wd_b = (uint16_t*)(ws + CTRL + XgB + W1B);
    size_t rem = ws_size - fixed;

    // choose P-buffer mode (store + combine) vs atomic mode
    int TcP = (rem > PB) ? (int)((rem - PB) / TILEB) : 0;
    if (TcP > MAXT) TcP = MAXT;
    bool useP = (TcP >= 24);
    float* Pbuf = nullptr;
    uint16_t* hbuf;
    int Tc;
    if (useP) {
        Pbuf = (float*)(ws + fixed);
        hbuf = (uint16_t*)(ws + fixed + PB);
        Tc = TcP;
    } else {
        hbuf = (uint16_t*)(ws + fixed);
        Tc = (int)(rem / TILEB);
        if (Tc > MAXT) Tc = MAXT;
        hipMemsetAsync(d_out, 0, (size_t)(out_size - 1) * 4, stream);  // atomics need zeroed out
    }
    int nchunks = (MAXT + Tc - 1) / Tc;
    Tc = (MAXT + nchunks - 1) / nchunks;   // even split

    long long n = (long long)Ee * Ff * Dd;
    conv_w1_kernel<<<11264, 256, 0, stream>>>(wgate, wup, W1b);
    conv_kernel<<<11264, 256, 0, stream>>>(wdown, wd_b, n);
    gather_kernel<<<Pp / 4, 256, 0, stream>>>(x, token_id, Xg);

    int nwg1 = Tc * 22;   // 5632/256 n-tiles
    int nwg2 = Tc * 8;    // 1024/128 n-tiles
    for (int c = 0; c < nchunks; ++c) {
        int tile0 = c * Tc;
        gemm_pipe<16, 256, 0><<<nwg1, 512, 0, stream>>>(
            Xg, W1b, seg_off, tile_e, tile_row0, ntiles, token_id, pair_w,
            hbuf, Pbuf, out, tile0, Tc, nwg1);
        if (useP) {
            gemm_pipe<44, 128, 1><<<nwg2, 512, 0, stream>>>(
                hbuf, wd_b, seg_off, tile_e, tile_row0, ntiles, token_id, pair_w,
                hbuf, Pbuf, out, tile0, Tc, nwg2);
        } else {
            gemm_pipe<44, 128, 2><<<nwg2, 512, 0, stream>>>(
                hbuf, wd_b, seg_off, tile_e, tile_row0, ntiles, token_id, pair_w,
                hbuf, Pbuf, out, tile0, Tc, nwg2);
        }
    }
    if (useP)
        combine_kernel<<<Tt, 256, 0, stream>>>(Pbuf, pos, tok_w, out);
}

// Round 7
// 754.496 us; speedup vs baseline: 1.0500x; 1.0500x over previous
//
#include <hip/hip_runtime.h>
#include <hip/hip_bf16.h>
#include <stdint.h>

// Problem dims
#define Dd 1024
#define Ee 8
#define Ff 2816
#define Tt 8192    // B*S tokens
#define Pp 16384   // Tt * K pairs

#define BMT 128            // M tile
#define MAXT 136           // max M-tiles: Pp/128 + Ee

using bf16x8 = __attribute__((ext_vector_type(8))) short;
using f32x4  = __attribute__((ext_vector_type(4))) float;

__device__ __forceinline__ uint16_t f2bf(float f) {
    union { float f; uint32_t u; } v; v.f = f;
    return (uint16_t)((v.u + 0x7fffu + ((v.u >> 16) & 1u)) >> 16);
}
__device__ __forceinline__ uint32_t pack2(float a, float b) {
    return (uint32_t)f2bf(a) | ((uint32_t)f2bf(b) << 16);
}
__device__ __forceinline__ uint4 pack8(float4 a, float4 b) {
    uint4 r; r.x = pack2(a.x, a.y); r.y = pack2(a.z, a.w);
    r.z = pack2(b.x, b.y); r.w = pack2(b.z, b.w); return r;
}
// XOR swizzle within a 128B LDS row (G4)
__device__ __forceinline__ int swz(int row, int cb) {
    return row * 128 + (cb ^ ((row & 7) << 4));
}
__device__ __forceinline__ void gload16(const void* g, void* lds) {
    __builtin_amdgcn_global_load_lds(
        (const __attribute__((address_space(1))) uint32_t*)(uintptr_t)g,
        (__attribute__((address_space(3))) uint32_t*)(uintptr_t)lds,
        16, 0, 0);
}
__device__ __forceinline__ int xcd_swz(int b, int nwg) {
    int xcd = b & 7, pos = b >> 3;
    int q = nwg >> 3, r = nwg & 7;
    return (xcd < r ? xcd * (q + 1) : r * (q + 1) + (xcd - r) * q) + pos;
}

// ---------------- Router ----------------
__global__ __launch_bounds__(256) void router_kernel(
    const float* __restrict__ x, const float* __restrict__ gw,
    float* __restrict__ usage_bank, int* __restrict__ counts,
    int* __restrict__ tok_i, float* __restrict__ tok_w)
{
    __shared__ float us[Ee];
    int tid = threadIdx.x;
    if (tid < Ee) us[tid] = 0.f;
    __syncthreads();
    int wave = tid >> 6, lane = tid & 63;
    int t = blockIdx.x * 4 + wave;

    float xr[16];
    const float* xp = x + (size_t)t * Dd;
    #pragma unroll
    for (int j = 0; j < 16; ++j) xr[j] = xp[lane + 64 * j];

    float logits[Ee];
    #pragma unroll
    for (int e = 0; e < Ee; ++e) {
        const float* gp = gw + e * Dd;
        float s = 0.f;
        #pragma unroll
        for (int j = 0; j < 16; ++j) s += xr[j] * gp[lane + 64 * j];
        #pragma unroll
        for (int m = 1; m < 64; m <<= 1) s += __shfl_xor(s, m, 64);
        logits[e] = s;
    }
    float v1 = -1e30f, v2 = -1e30f; int i1 = 0, i2 = 0;
    #pragma unroll
    for (int e = 0; e < Ee; ++e) {
        float l = logits[e];
        if (l > v1) { v2 = v1; i2 = i1; v1 = l; i1 = e; }
        else if (l > v2) { v2 = l; i2 = e; }
    }
    float ex2 = expf(v2 - v1);
    float w1 = 1.f / (1.f + ex2);
    float w2 = ex2 * w1;
    float p[Ee]; float se = 0.f;
    #pragma unroll
    for (int e = 0; e < Ee; ++e) { p[e] = expf(logits[e] - v1); se += p[e]; }
    float inv = 1.f / se;
    if (lane == 0) {
        #pragma unroll
        for (int e = 0; e < Ee; ++e) atomicAdd(&us[e], p[e] * inv);
        atomicAdd(&counts[i1], 1);
        atomicAdd(&counts[i2], 1);
        tok_i[t * 2] = i1; tok_i[t * 2 + 1] = i2;
        tok_w[t * 2] = w1; tok_w[t * 2 + 1] = w2;
    }
    __syncthreads();
    if (tid < Ee) atomicAdd(&usage_bank[(blockIdx.x & 63) * Ee + tid], us[tid]);
}

// ---------------- Scan: aux + offsets + tile list ----------------
__global__ void scan_kernel(const float* __restrict__ usage_bank,
                            const int* __restrict__ counts,
                            int* __restrict__ seg_off, int* __restrict__ cursor,
                            int* __restrict__ ntiles, int* __restrict__ tile_e,
                            int* __restrict__ tile_row0, float* __restrict__ out_aux)
{
    int tid = threadIdx.x;
    __shared__ float us[Ee];
    if (tid < Ee) {
        float s = 0.f;
        for (int b = 0; b < 64; ++b) s += usage_bank[b * Ee + tid];
        us[tid] = s / (float)Tt;
    }
    __syncthreads();
    if (tid == 0) {
        float aux = 0.f;
        for (int e = 0; e < Ee; ++e) { float d = us[e] - 0.125f; aux += d * d; }
        *out_aux = aux;
        int off = 0;
        for (int e = 0; e < Ee; ++e) { seg_off[e] = off; cursor[e] = off; off += counts[e]; }
        seg_off[Ee] = off;
        int ti = 0;
        for (int e = 0; e < Ee; ++e) {
            int so = seg_off[e], cnt = counts[e];
            for (int r = 0; r < cnt; r += BMT) { tile_e[ti] = e; tile_row0[ti] = so + r; ++ti; }
        }
        *ntiles = ti;   // <= MAXT
    }
}

// ---------------- Build pair lists (+ token->slot map) ----------------
__global__ __launch_bounds__(256) void build_kernel(
    const int* __restrict__ tok_i, const float* __restrict__ tok_w,
    int* __restrict__ cursor, int* __restrict__ token_id, float* __restrict__ pair_w,
    int* __restrict__ pos)
{
    int t = blockIdx.x * 256 + threadIdx.x;
    if (t >= Tt) return;
    int i1 = tok_i[t * 2], i2 = tok_i[t * 2 + 1];
    int s1 = atomicAdd(&cursor[i1], 1);
    token_id[s1] = t; pair_w[s1] = tok_w[t * 2];     pos[t * 2] = s1;
    int s2 = atomicAdd(&cursor[i2], 1);
    token_id[s2] = t; pair_w[s2] = tok_w[t * 2 + 1]; pos[t * 2 + 1] = s2;
}

// ---------------- Gather x rows -> bf16 Xg[pair, D] ----------------
__global__ __launch_bounds__(256) void gather_kernel(
    const float* __restrict__ x, const int* __restrict__ token_id,
    uint16_t* __restrict__ Xg)
{
    int wave = threadIdx.x >> 6, lane = threadIdx.x & 63;
    int r = blockIdx.x * 4 + wave;
    if (r >= Pp) return;
    int t = token_id[r];
    const float4* src = (const float4*)(x + (size_t)t * Dd) + lane * 4;
    float4 f0 = src[0], f1 = src[1], f2 = src[2], f3 = src[3];
    uint4* dst = (uint4*)(Xg + (size_t)r * Dd) + lane * 2;
    dst[0] = pack8(f0, f1);
    dst[1] = pack8(f2, f3);
}

// ---------------- All weights fp32 -> bf16 (gate/up interleaved + wd plain) ----------------
// W1b[e] has 5632 rows: row (f>>4)*32 + (f&15) = gate f ; +16 = up f.
__global__ __launch_bounds__(256) void conv_all_kernel(
    const float* __restrict__ gsrc, const float* __restrict__ usrc,
    const float* __restrict__ dsrc, uint16_t* __restrict__ w1b,
    uint16_t* __restrict__ wdb)
{
    long long i = ((long long)blockIdx.x * 256 + threadIdx.x) * 8;
    if (i >= (long long)Ee * Ff * Dd) return;
    int d = (int)(i & (Dd - 1));
    long long row = i >> 10;            // e*Ff + f
    int e = (int)(row / Ff), f = (int)(row - (long long)e * Ff);
    size_t rg = (size_t)e * 5632 + (size_t)(f >> 4) * 32 + (f & 15);
    const float4* sg = (const float4*)(gsrc + i);
    *(uint4*)(w1b + rg * 1024 + d) = pack8(sg[0], sg[1]);
    const float4* su = (const float4*)(usrc + i);
    *(uint4*)(w1b + (rg + 16) * 1024 + d) = pack8(su[0], su[1]);
    const float4* sd = (const float4*)(dsrc + i);
    *(uint4*)(wdb + i) = pack8(sd[0], sd[1]);
}

// ---------------- m97-style GEMM: BM=128, BN=128, BK=64, 4 waves ----------------
// Single-buffered LDS (32 KB), 2-barrier loop, global_load_lds staging,
// 3 blocks/CU co-residency provides the implicit pipeline (m114).
// MODE 0: gemm1 (A=Xg, B=W1b interleaved; epilogue h=silu(g)*u -> hbuf bf16)
// MODE 1: gemm2 (A=hbuf, B=wd_b; epilogue P[pr] fp32 store)
// MODE 2: gemm2 atomic (epilogue atomicAdd into out)
template<int NKT, int MODE>
__global__ __launch_bounds__(256, 3) void gemm_m97(
    const uint16_t* __restrict__ Abase, const uint16_t* __restrict__ Bbase,
    const int* __restrict__ seg_off, const int* __restrict__ tile_e,
    const int* __restrict__ tile_row0, const int* __restrict__ ntiles,
    const int* __restrict__ token_id, const float* __restrict__ pair_w,
    uint16_t* __restrict__ hbuf, float* __restrict__ Pbuf, float* __restrict__ out,
    int tile0, int Tc, int nwg)
{
    constexpr int LD = (MODE == 0) ? Dd : Ff;

    int wgid = xcd_swz(blockIdx.x, nwg);
    int nt = wgid / Tc, lt = wgid - nt * Tc;
    int tidx = tile0 + lt;
    if (tidx >= *ntiles) return;
    int e = tile_e[tidx];
    int row0 = tile_row0[tidx];
    int rows = seg_off[e + 1] - row0; if (rows > BMT) rows = BMT;
    int slot = lt * BMT;

    __shared__ uint4 lds4[32768 / 16];   // A 16K | B 16K
    char* smA = (char*)lds4;
    char* smB = smA + 16384;

    int tid = threadIdx.x, lane = tid & 63, wv = tid >> 6;
    int wr = wv >> 1, wc = wv & 1;

    // staging sources: per-lane inverse-swizzled (rule #21: LDS dest linear)
    int srow = wv * 32 + (lane >> 3);            // wave stages rows [wv*32, wv*32+32)
    int csw = ((lane & 7) ^ (lane >> 3)) * 8;    // source col chunk (elements)
    const uint16_t* aP;
    const uint16_t* bP;
    if constexpr (MODE == 0) {
        aP = Abase + (size_t)(row0 + srow) * LD + csw;
        bP = Bbase + ((size_t)e * 5632 + nt * 128 + srow) * LD + csw;
    } else {
        aP = Abase + (size_t)(slot + srow) * LD + csw;
        bP = Bbase + ((size_t)e * Dd + nt * 128 + srow) * LD + csw;
    }
    char* aL = smA + wv * 4096;
    char* bL = smB + wv * 4096;

    f32x4 acc[4][4];
    f32x4 zero4 = {0.f, 0.f, 0.f, 0.f};
    #pragma unroll
    for (int m = 0; m < 4; ++m)
        #pragma unroll
        for (int n = 0; n < 4; ++n) acc[m][n] = zero4;

    #pragma unroll 1
    for (int kt = 0; kt < NKT; ++kt) {
        // stage tile kt (8 gload16/wave); __syncthreads drains vmcnt+lgkm
        #pragma unroll
        for (int i = 0; i < 4; ++i) {
            gload16(aP + (size_t)(i * 8) * LD + kt * 64, aL + i * 1024);
            gload16(bP + (size_t)(i * 8) * LD + kt * 64, bL + i * 1024);
        }
        __syncthreads();
        #pragma unroll
        for (int kk = 0; kk < 2; ++kk) {
            int cb = kk * 64 + ((lane >> 4) << 4);
            bf16x8 a[4], b[4];
            #pragma unroll
            for (int m = 0; m < 4; ++m)
                a[m] = *(const bf16x8*)(smA + swz(wr * 64 + m * 16 + (lane & 15), cb));
            #pragma unroll
            for (int n = 0; n < 4; ++n)
                b[n] = *(const bf16x8*)(smB + swz(wc * 64 + n * 16 + (lane & 15), cb));
            #pragma unroll
            for (int m = 0; m < 4; ++m)
                #pragma unroll
                for (int n = 0; n < 4; ++n)
                    acc[m][n] = __builtin_amdgcn_mfma_f32_16x16x32_bf16(a[m], b[n], acc[m][n], 0, 0, 0);
        }
        __syncthreads();   // all waves done reading before next stage overwrites
    }

    if constexpr (MODE == 0) {
        // interleaved n-frags: (0,1)=(g,u) at f0, (2,3)=(g,u) at f0+16
        int hc = nt * 64 + wc * 32 + (lane & 15);
        #pragma unroll
        for (int m = 0; m < 4; ++m) {
            #pragma unroll
            for (int g = 0; g < 4; ++g) {
                int rr = wr * 64 + m * 16 + (lane >> 4) * 4 + g;
                if (rr < rows) {
                    uint16_t* hp = hbuf + (size_t)(slot + rr) * Ff + hc;
                    float g0 = acc[m][0][g], u0 = acc[m][1][g];
                    hp[0]  = f2bf(g0 * u0 / (1.f + expf(-g0)));
                    float g1 = acc[m][2][g], u1 = acc[m][3][g];
                    hp[16] = f2bf(g1 * u1 / (1.f + expf(-g1)));
                }
            }
        }
    } else if constexpr (MODE == 1) {
        int col = nt * 128 + wc * 64 + (lane & 15);
        #pragma unroll
        for (int m = 0; m < 4; ++m) {
            #pragma unroll
            for (int g = 0; g < 4; ++g) {
                int rr = wr * 64 + m * 16 + (lane >> 4) * 4 + g;
                if (rr < rows) {
                    float* pp = Pbuf + (size_t)(row0 + rr) * Dd + col;
                    pp[0]  = acc[m][0][g];
                    pp[16] = acc[m][1][g];
                    pp[32] = acc[m][2][g];
                    pp[48] = acc[m][3][g];
                }
            }
        }
    } else {
        int col = nt * 128 + wc * 64 + (lane & 15);
        #pragma unroll
        for (int m = 0; m < 4; ++m) {
            #pragma unroll
            for (int g = 0; g < 4; ++g) {
                int rr = wr * 64 + m * 16 + (lane >> 4) * 4 + g;
                if (rr < rows) {
                    int pr = row0 + rr;
                    int tok = token_id[pr];
                    float w = pair_w[pr];
                    float* op = out + (size_t)tok * Dd + col;
                    atomicAdd(op + 0,  w * acc[m][0][g]);
                    atomicAdd(op + 16, w * acc[m][1][g]);
                    atomicAdd(op + 32, w * acc[m][2][g]);
                    atomicAdd(op + 48, w * acc[m][3][g]);
                }
            }
        }
    }
}

// ---------------- Combine: out[t] = w1*P[s1] + w2*P[s2] ----------------
__global__ __launch_bounds__(256) void combine_kernel(
    const float* __restrict__ P, const int* __restrict__ pos,
    const float* __restrict__ tok_w, float* __restrict__ out)
{
    int t = blockIdx.x;
    int d = threadIdx.x * 4;
    int s1 = pos[t * 2], s2 = pos[t * 2 + 1];
    float w1 = tok_w[t * 2], w2 = tok_w[t * 2 + 1];
    float4 a = *(const float4*)(P + (size_t)s1 * Dd + d);
    float4 b = *(const float4*)(P + (size_t)s2 * Dd + d);
    float4 o;
    o.x = w1 * a.x + w2 * b.x; o.y = w1 * a.y + w2 * b.y;
    o.z = w1 * a.z + w2 * b.z; o.w = w1 * a.w + w2 * b.w;
    *(float4*)(out + (size_t)t * Dd + d) = o;
}

// ---------------- Host launch ----------------
extern "C" void kernel_launch(void* const* d_in, const int* in_sizes, int n_in,
                              void* d_out, int out_size, void* d_ws, size_t ws_size,
                              hipStream_t stream)
{
    const float* x     = (const float*)d_in[0];
    const float* gw    = (const float*)d_in[1];
    const float* wgate = (const float*)d_in[2];
    const float* wup   = (const float*)d_in[3];
    const float* wdown = (const float*)d_in[4];
    float* out = (float*)d_out;

    char* ws = (char*)d_ws;
    float* usage_bank = (float*)(ws);
    int*   counts     = (int*)(ws + 2048);
    int*   seg_off    = (int*)(ws + 2112);
    int*   cursor     = (int*)(ws + 2176);
    int*   ntiles     = (int*)(ws + 2240);
    int*   tile_e     = (int*)(ws + 4096);
    int*   tile_row0  = (int*)(ws + 5120);
    int*   tok_i      = (int*)(ws + 8192);
    float* tok_w      = (float*)(ws + 73728);
    int*   token_id   = (int*)(ws + 139264);
    float* pair_w     = (float*)(ws + 204800);
    int*   pos        = (int*)(ws + 270336);
    const size_t CTRL  = 335872;
    const size_t TILEB = (size_t)BMT * Ff * 2;          // 720,896 B per h-tile
    const size_t XgB   = (size_t)(Pp + BMT) * Dd * 2;   // 33.8 MB (padded)
    const size_t W1B   = 2ull * Ee * Ff * Dd * 2;       // 92.3 MB interleaved gate/up
    const size_t WDB   = (size_t)Ee * Dd * Ff * 2;      // 46.1 MB
    const size_t PB    = (size_t)Pp * Dd * 4;           // 67.1 MB fp32 per-pair rows

    if (ws_size >= 4096) hipMemsetAsync(ws, 0, 4096, stream);
    size_t fixed = CTRL + XgB + W1B + WDB;
    if (ws_size < fixed + TILEB) {   // cannot run the fast path; fail gracefully (no OOB)
        hipMemsetAsync(d_out, 0, (size_t)out_size * 4, stream);
        return;
    }

    router_kernel<<<Tt / 4, 256, 0, stream>>>(x, gw, usage_bank, counts, tok_i, tok_w);
    scan_kernel<<<1, 64, 0, stream>>>(usage_bank, counts, seg_off, cursor,
                                      ntiles, tile_e, tile_row0, out + (out_size - 1));
    build_kernel<<<Tt / 256, 256, 0, stream>>>(tok_i, tok_w, cursor, token_id, pair_w, pos);

    uint16_t* Xg   = (uint16_t*)(ws + CTRL);
    uint16_t* W1b  = (uint16_t*)(ws + CTRL + XgB);
    uint16_t* wd_b = (uint16_t*)(ws + CTRL + XgB + W1B);
    size_t rem = ws_size - fixed;

    // choose P-buffer mode (store + combine) vs atomic mode
    int TcP = (rem > PB) ? (int)((rem - PB) / TILEB) : 0;
    if (TcP > MAXT) TcP = MAXT;
    bool useP = (TcP >= 24);
    float* Pbuf = nullptr;
    uint16_t* hbuf;
    int Tc;
    if (useP) {
        Pbuf = (float*)(ws + fixed);
        hbuf = (uint16_t*)(ws + fixed + PB);
        Tc = TcP;
    } else {
        hbuf = (uint16_t*)(ws + fixed);
        Tc = (int)(rem / TILEB);
        if (Tc > MAXT) Tc = MAXT;
        hipMemsetAsync(d_out, 0, (size_t)(out_size - 1) * 4, stream);  // atomics need zeroed out
    }
    int nchunks = (MAXT + Tc - 1) / Tc;
    Tc = (MAXT + nchunks - 1) / nchunks;   // even split

    conv_all_kernel<<<11264, 256, 0, stream>>>(wgate, wup, wdown, W1b, wd_b);
    gather_kernel<<<Pp / 4, 256, 0, stream>>>(x, token_id, Xg);

    int nwg1 = Tc * 44;   // 5632/128 interleaved n-tiles
    int nwg2 = Tc * 8;    // 1024/128 n-tiles
    for (int c = 0; c < nchunks; ++c) {
        int tile0 = c * Tc;
        gemm_m97<16, 0><<<nwg1, 256, 0, stream>>>(
            Xg, W1b, seg_off, tile_e, tile_row0, ntiles, token_id, pair_w,
            hbuf, Pbuf, out, tile0, Tc, nwg1);
        if (useP) {
            gemm_m97<44, 1><<<nwg2, 256, 0, stream>>>(
                hbuf, wd_b, seg_off, tile_e, tile_row0, ntiles, token_id, pair_w,
                hbuf, Pbuf, out, tile0, Tc, nwg2);
        } else {
            gemm_m97<44, 2><<<nwg2, 256, 0, stream>>>(
                hbuf, wd_b, seg_off, tile_e, tile_row0, ntiles, token_id, pair_w,
                hbuf, Pbuf, out, tile0, Tc, nwg2);
        }
    }
    if (useP)
        combine_kernel<<<Tt, 256, 0, stream>>>(Pbuf, pos, tok_w, out);
}